// Round 5
// baseline (988.781 us; speedup 1.0000x reference)
//
#include <hip/hip_runtime.h>
#include <hip/hip_bf16.h>

typedef unsigned short u16;

#define NN 400
#define NB 10
#define NC 1000
#define CFD 24
#define NFD 85
#define NFROW 86
#define SEDIM 4
#define OEDIM 32
#define XND 121   // 85 + 4 + 32
#define EE 800
#define N_SHAPE_GUARD 7

// bf16 bit helpers (exact load; RNE store)
__device__ __forceinline__ float b2f(u16 u) { return __uint_as_float((unsigned)u << 16); }
__device__ __forceinline__ u16 f2b(float v) {
  unsigned x = __float_as_uint(v);
  return (u16)((x + 0x7fff + ((x >> 16) & 1)) >> 16);
}
// runtime-dtype INPUT load: fz=1 -> underlying fp32, fz=0 -> underlying bf16
__device__ __forceinline__ float ldf(const void* p, int idx, int fz) {
  if (fz) return ((const float*)p)[idx];
  return b2f(((const u16*)p)[idx]);
}
// runtime-dtype OUTPUT store (matches input dtype: uniform-dtype problem)
__device__ __forceinline__ void stf(void* p, int idx, int fz, float v) {
  if (fz) { ((float*)p)[idx] = v; return; }
  ((u16*)p)[idx] = f2b(v);
}

// ---------------- dtype detector: read W1 as bf16; fp32 data -> wild exponents
__global__ void k_detect(const u16* __restrict__ w, int* __restrict__ flag) {
  int t = threadIdx.x;
  int wild = 0;
  for (int j = t; j < 512; j += 64) {
    float a = fabsf(b2f(w[j]));
    if (!(a < 1e4f)) wild++;          // huge / inf / NaN
  }
  #pragma unroll
  for (int off = 32; off; off >>= 1) wild += __shfl_xor(wild, off);
  if (t == 0) *flag = (wild > 16) ? 1 : 0;   // 1 => inputs are float32
}

// ---------------- prep: A_node = concat(cont, shape_emb, op_emb) @ W1[:121] + b1
__global__ void k_prep(const void* __restrict__ node_feat, const int* __restrict__ opcode,
                       const void* __restrict__ op_emb, const void* __restrict__ shape_emb,
                       const void* __restrict__ W1, const void* __restrict__ b1,
                       const int* __restrict__ dflag, float* __restrict__ A_node) {
  __shared__ float xn[128];
  int fz = *dflag;
  int i = blockIdx.x, t = threadIdx.x;
  float v = 0.f;
  if (t < NFD) {
    v = ldf(node_feat, i*NFROW + t, fz);
  } else if (t < NFD + SEDIM) {
    int st = (int)ldf(node_feat, i*NFROW + NFD, fz);
    st = min(max(st, 0), N_SHAPE_GUARD);
    v = ldf(shape_emb, st*SEDIM + (t - NFD), fz);
  } else if (t < XND) {
    int oc = min(max(opcode[i], 0), 119);
    v = ldf(op_emb, oc*OEDIM + (t - NFD - SEDIM), fz);
  }
  xn[t] = v;
  __syncthreads();
  float acc = ldf(b1, t, fz);
  for (int k = 0; k < XND; k++) acc += xn[k] * ldf(W1, k*128 + t, fz);
  A_node[i*128 + t] = acc;
}

// ---------------- C_cfg = config_feat @ W1[121:145]   (10000 x 128)
__global__ void k_cfg(const void* __restrict__ cfg, const void* __restrict__ W1,
                      const int* __restrict__ dflag, float* __restrict__ C_cfg) {
  int fz = *dflag;
  int r = blockIdx.x, t = threadIdx.x;
  __shared__ float cs[CFD];
  if (t < CFD) cs[t] = ldf(cfg, r*CFD + t, fz);
  __syncthreads();
  float acc = 0.f;
  for (int k = 0; k < CFD; k++) acc += cs[k] * ldf(W1, (XND + k)*128 + t, fz);
  C_cfg[r*128 + t] = acc;
}

// ---------------- pack weights to fp32: W2f (128x128), Wc{0,1,2} = [Wl|Wr]
__global__ void k_wpack(const void* __restrict__ W2,
                        const void* __restrict__ Wl0, const void* __restrict__ Wr0,
                        const void* __restrict__ Wl1, const void* __restrict__ Wr1,
                        const void* __restrict__ Wl2, const void* __restrict__ Wr2,
                        const int* __restrict__ dflag,
                        float* __restrict__ W2f, float* __restrict__ Wc0,
                        float* __restrict__ Wc1, float* __restrict__ Wc2) {
  int fz = *dflag;
  int idx = blockIdx.x * 256 + threadIdx.x;
  if (idx < 16384) { W2f[idx] = ldf(W2, idx, fz); return; }
  idx -= 16384;
  if (idx < 16384) { int k = idx >> 7, n = idx & 127;
    Wc0[idx] = (n < 64) ? ldf(Wl0, k*64 + n, fz) : ldf(Wr0, k*64 + n - 64, fz); return; }
  idx -= 16384;
  if (idx < 8192) { int k = idx >> 7, n = idx & 127;
    Wc1[idx] = (n < 64) ? ldf(Wl1, k*64 + n, fz) : ldf(Wr1, k*64 + n - 64, fz); return; }
  idx -= 8192;
  if (idx < 8192) { int k = idx >> 7, n = idx & 127;
    Wc2[idx] = (n < 64) ? ldf(Wl2, k*64 + n, fz) : ldf(Wr2, k*64 + n - 64, fz); return; }
}

// ---------------- build CSR (in-edges per dst) + degree
__global__ void k_csr(const int* __restrict__ edge_index, int* __restrict__ offs,
                      int* __restrict__ srcl, float* __restrict__ deg) {
  __shared__ int cnt[NN];
  __shared__ int offl[NN + 1];
  int t = threadIdx.x;
  for (int i = t; i < NN; i += 256) cnt[i] = 0;
  __syncthreads();
  for (int e = t; e < EE; e += 256) {
    int d = edge_index[EE + e] & 511; if (d < NN) atomicAdd(&cnt[d], 1);
  }
  __syncthreads();
  if (t == 0) {
    int s = 0;
    for (int i = 0; i < NN; i++) { offl[i] = s; s += cnt[i]; }
    offl[NN] = s;
  }
  __syncthreads();
  for (int i = t; i < NN; i += 256) { deg[i] = (float)cnt[i]; cnt[i] = offl[i]; }
  for (int i = t; i < NN + 1; i += 256) offs[i] = offl[i];
  __syncthreads();
  for (int e = t; e < EE; e += 256) {
    int d = edge_index[EE + e] & 511;
    if (d < NN) {
      int p = atomicAdd(&cnt[d], 1);
      srcl[p] = min(max(edge_index[e], 0), NN - 1);
    }
  }
}

// ---------------- tall-skinny GEMM: Out(M x 128) = A(M x K) @ B(K x 128)
// fp32 accumulate, bf16 A-storage and bf16 Out-storage (workspace format)
// BUILD: A row = relu(A_node[i] + C_cfg[batch[i],c])  (factored W1 + relu join)
// In-place safe when Out==In: block's A-tile fully staged in LDS before stores,
// blocks own disjoint row ranges. (No __restrict__ on In/Out for that reason.)
template<int K, bool BUILD, bool BIASRELU>
__global__ __launch_bounds__(256) void k_gemm(
    const u16* In,
    const float* __restrict__ A_node, const float* __restrict__ C_cfg,
    const int* __restrict__ batch,
    const float* __restrict__ Bf, const void* __restrict__ bias,
    const int* __restrict__ dflag, u16* Out) {
  const int MT = 40;
  __shared__ float AsT[K][MT + 1];   // transposed, padded (conflict-free)
  __shared__ float Bs[32 * 128];
  __shared__ float an[128];
  int blk = blockIdx.x;
  int i = blk / 25, c0 = (blk % 25) * MT;
  int t = threadIdx.x;
  size_t row0 = (size_t)i * NC + c0;

  if (BUILD) {
    if (t < 128) an[t] = A_node[i*128 + t];
    __syncthreads();
    int b = batch[i] % NB;
    size_t crow0 = (size_t)b * NC + c0;
    for (int f = t; f < MT * K; f += 256) {
      int m = f / K, k = f % K;
      float v = an[k] + C_cfg[(crow0 + m)*128 + k];
      AsT[k][m] = fmaxf(v, 0.f);
    }
  } else {
    const int K4 = K / 4;
    for (int f = t; f < MT * K4; f += 256) {
      int m = f / K4, kp = f % K4;
      ushort4 u = reinterpret_cast<const ushort4*>(In + (row0 + m) * (size_t)K)[kp];
      AsT[4*kp + 0][m] = b2f(u.x);
      AsT[4*kp + 1][m] = b2f(u.y);
      AsT[4*kp + 2][m] = b2f(u.z);
      AsT[4*kp + 3][m] = b2f(u.w);
    }
  }

  float acc[5][4] = {};
  int n4 = (t & 31) * 4;
  int m0 = (t >> 5) * 5;

  for (int kc = 0; kc < K / 32; kc++) {
    __syncthreads();
    for (int f = t; f < 32 * 128; f += 256) Bs[f] = Bf[kc*32*128 + f];
    __syncthreads();
    #pragma unroll 4
    for (int kk = 0; kk < 32; kk++) {
      int k = kc*32 + kk;
      float4 w = *(const float4*)&Bs[kk*128 + n4];
      float a0 = AsT[k][m0 + 0];
      float a1 = AsT[k][m0 + 1];
      float a2 = AsT[k][m0 + 2];
      float a3 = AsT[k][m0 + 3];
      float a4 = AsT[k][m0 + 4];
      acc[0][0] += a0*w.x; acc[0][1] += a0*w.y; acc[0][2] += a0*w.z; acc[0][3] += a0*w.w;
      acc[1][0] += a1*w.x; acc[1][1] += a1*w.y; acc[1][2] += a1*w.z; acc[1][3] += a1*w.w;
      acc[2][0] += a2*w.x; acc[2][1] += a2*w.y; acc[2][2] += a2*w.z; acc[2][3] += a2*w.w;
      acc[3][0] += a3*w.x; acc[3][1] += a3*w.y; acc[3][2] += a3*w.z; acc[3][3] += a3*w.w;
      acc[4][0] += a4*w.x; acc[4][1] += a4*w.y; acc[4][2] += a4*w.z; acc[4][3] += a4*w.w;
    }
  }

  float bv[4] = {0.f, 0.f, 0.f, 0.f};
  if (BIASRELU) {
    int fz = *dflag;
    bv[0] = ldf(bias, n4, fz);     bv[1] = ldf(bias, n4 + 1, fz);
    bv[2] = ldf(bias, n4 + 2, fz); bv[3] = ldf(bias, n4 + 3, fz);
  }
  #pragma unroll
  for (int j = 0; j < 5; j++) {
    size_t r = row0 + m0 + j;
    ushort4 st;
    float v0 = acc[j][0], v1 = acc[j][1], v2 = acc[j][2], v3 = acc[j][3];
    if (BIASRELU) {
      v0 = fmaxf(v0 + bv[0], 0.f); v1 = fmaxf(v1 + bv[1], 0.f);
      v2 = fmaxf(v2 + bv[2], 0.f); v3 = fmaxf(v3 + bv[3], 0.f);
    }
    st.x = f2b(v0); st.y = f2b(v1); st.z = f2b(v2); st.w = f2b(v3);
    *reinterpret_cast<ushort4*>(Out + r*128 + n4) = st;
  }
}

// ---------------- SAGE combine: x_next = relu(y + (sum_z over in-edges)/max(deg,1) + bg)
// yz: row (i*NC+c)*128, y at [0:64], z at [64:128]; xout row stride 64 (bf16)
__global__ __launch_bounds__(256) void k_agg(
    const u16* __restrict__ yz, const int* __restrict__ offs, const int* __restrict__ srcl,
    const float* __restrict__ deg, const void* __restrict__ bg,
    const int* __restrict__ dflag, u16* __restrict__ xout) {
  int fz = *dflag;
  int blk = blockIdx.x;
  int i = blk / (NC/4), cb = blk % (NC/4);
  int t = threadIdx.x, h = t & 63;
  int c = cb*4 + (t >> 6);
  int o0 = offs[i], o1 = offs[i + 1];
  float acc = 0.f;
  for (int e = o0; e < o1; e++) {
    int s = srcl[e];
    acc += b2f(yz[((size_t)s*NC + c)*128 + 64 + h]);
  }
  float d = fmaxf(deg[i], 1.f);
  float y = b2f(yz[((size_t)i*NC + c)*128 + h]);
  float v = y + acc / d + ldf(bg, h, fz);
  xout[((size_t)i*NC + c)*64 + h] = f2b(fmaxf(v, 0.f));
}

// ---------------- pool (max + mean over 40 nodes) -> L2 norm -> MLP head
// output dtype follows the detected input dtype (fz=1 -> fp32, fz=0 -> bf16)
__global__ __launch_bounds__(256) void k_pool(
    const u16* __restrict__ x, const void* __restrict__ Wp1, const void* __restrict__ bp1,
    const void* __restrict__ Wp2, const void* __restrict__ bp2,
    const int* __restrict__ dflag, void* __restrict__ out) {
  int fz = *dflag;
  int b = blockIdx.x / (NC/4);
  int cb = blockIdx.x % (NC/4);
  int t = threadIdx.x;
  int h = t & 63;
  int w = t >> 6;                 // one wave = one config
  int c = cb*4 + w;
  __shared__ float wp1[64*32];
  __shared__ float bp1s[32], wp2s[32];
  __shared__ float xs[4][64];
  for (int f = t; f < 2048; f += 256) wp1[f] = ldf(Wp1, f, fz);
  if (t < 32) { bp1s[t] = ldf(bp1, t, fz); wp2s[t] = ldf(Wp2, t, fz); }
  float mx = -3.0e38f, sm = 0.f;
  for (int j = 0; j < 40; j++) {
    float v = b2f(x[((size_t)(b*40 + j)*NC + c)*64 + h]);
    mx = fmaxf(mx, v); sm += v;
  }
  float g = mx + sm * (1.f / 40.f);
  float sq = g * g;
  #pragma unroll
  for (int off = 32; off; off >>= 1) sq += __shfl_xor(sq, off);
  float gn = g * rsqrtf(sq);
  xs[w][h] = gn;
  __syncthreads();
  int j32 = h & 31;
  float hj = bp1s[j32];
  const float* xr = xs[w];
  for (int k = 0; k < 64; k++) hj += xr[k] * wp1[k*32 + j32];
  hj = fmaxf(hj, 0.f);
  float contrib = hj * wp2s[j32];   // lanes 0-31 and 32-63 duplicate -> sum/2
  #pragma unroll
  for (int off = 32; off; off >>= 1) contrib += __shfl_xor(contrib, off);
  if (h == 0) stf(out, b*NC + c, fz, contrib * 0.5f + ldf(bp2, 0, fz));
}

extern "C" void kernel_launch(void* const* d_in, const int* in_sizes, int n_in,
                              void* d_out, int out_size, void* d_ws, size_t ws_size,
                              hipStream_t stream) {
  const void* node_feat   = d_in[0];
  const int*  node_opcode = (const int*)d_in[1];
  const void* config_feat = d_in[2];
  const int*  edge_index  = (const int*)d_in[3];
  const int*  batch       = (const int*)d_in[4];
  const void* op_emb      = d_in[5];
  const void* shape_emb   = d_in[6];
  const void* W1  = d_in[7];
  const void* b1  = d_in[8];
  const void* W2  = d_in[9];
  const void* b2  = d_in[10];
  const void* Wl0 = d_in[11];
  const void* Wr0 = d_in[12];
  const void* bg0 = d_in[13];
  const void* Wl1 = d_in[14];
  const void* Wr1 = d_in[15];
  const void* bg1 = d_in[16];
  const void* Wl2 = d_in[17];
  const void* Wr2 = d_in[18];
  const void* bg2 = d_in[19];
  const void* Wp1 = d_in[20];
  const void* bp1 = d_in[21];
  const void* Wp2 = d_in[22];
  const void* bp2 = d_in[23];

  // workspace: 159.1 MB total (210.3 MB ran in round 1; 312.9 MB faulted in round 2)
  char* p = (char*)d_ws;
  int*   flag   = (int*)p;   p += 256;
  float* A_node = (float*)p; p += 400*128*4;
  float* C_cfg  = (float*)p; p += 10000*128*4;
  float* W2f    = (float*)p; p += 128*128*4;
  float* Wc0    = (float*)p; p += 128*128*4;
  float* Wc1    = (float*)p; p += 64*128*4;
  float* Wc2    = (float*)p; p += 64*128*4;
  int*   offs   = (int*)p;   p += 2048;
  int*   srcl   = (int*)p;   p += 4096;
  float* deg    = (float*)p; p += 2048;
  u16*   BIG    = (u16*)p;   p += (size_t)400*1000*128*2;   // x2 / [y|z] (in-place), bf16
  u16*   X      = (u16*)p;   p += (size_t)400*1000*64*2;    // sage outputs, bf16

  k_detect<<<dim3(1), dim3(64), 0, stream>>>((const u16*)W1, flag);
  k_prep<<<dim3(400), dim3(128), 0, stream>>>(node_feat, node_opcode, op_emb, shape_emb, W1, b1, flag, A_node);
  k_cfg<<<dim3(10000), dim3(128), 0, stream>>>(config_feat, W1, flag, C_cfg);
  k_wpack<<<dim3(192), dim3(256), 0, stream>>>(W2, Wl0, Wr0, Wl1, Wr1, Wl2, Wr2, flag, W2f, Wc0, Wc1, Wc2);
  k_csr<<<dim3(1), dim3(256), 0, stream>>>(edge_index, offs, srcl, deg);

  // x2 = relu(relu(A_node + C_cfg) @ W2 + b2)            -> BIG (400k x 128)
  k_gemm<128, true, true><<<dim3(10000), dim3(256), 0, stream>>>(nullptr, A_node, C_cfg, batch, W2f, b2, flag, BIG);
  // sage0: [y|z] = x2 @ [Wl0|Wr0]   (in-place on BIG)
  k_gemm<128, false, false><<<dim3(10000), dim3(256), 0, stream>>>(BIG, nullptr, nullptr, nullptr, Wc0, nullptr, flag, BIG);
  k_agg<<<dim3(100000), dim3(256), 0, stream>>>(BIG, offs, srcl, deg, bg0, flag, X);
  // sage1
  k_gemm<64, false, false><<<dim3(10000), dim3(256), 0, stream>>>(X, nullptr, nullptr, nullptr, Wc1, nullptr, flag, BIG);
  k_agg<<<dim3(100000), dim3(256), 0, stream>>>(BIG, offs, srcl, deg, bg1, flag, X);
  // sage2
  k_gemm<64, false, false><<<dim3(10000), dim3(256), 0, stream>>>(X, nullptr, nullptr, nullptr, Wc2, nullptr, flag, BIG);
  k_agg<<<dim3(100000), dim3(256), 0, stream>>>(BIG, offs, srcl, deg, bg2, flag, X);
  // pool + norm + head
  k_pool<<<dim3(2500), dim3(256), 0, stream>>>(X, Wp1, bp1, Wp2, bp2, flag, d_out);
}

// Round 6
// 643.232 us; speedup vs baseline: 1.5372x; 1.5372x over previous
//
#include <hip/hip_runtime.h>
#include <hip/hip_bf16.h>

typedef unsigned short u16;
typedef short bf16x8 __attribute__((ext_vector_type(8)));   // 8 bf16 in 4 VGPRs
typedef float f32x4 __attribute__((ext_vector_type(4)));

#define NN 400
#define NB 10
#define NC 1000
#define CFD 24
#define NFD 85
#define NFROW 86
#define SEDIM 4
#define OEDIM 32
#define XND 121   // 85 + 4 + 32
#define EE 800
#define N_SHAPE_GUARD 7

// bf16 bit helpers (exact load; RNE store)
__device__ __forceinline__ float b2f(u16 u) { return __uint_as_float((unsigned)u << 16); }
__device__ __forceinline__ u16 f2b(float v) {
  unsigned x = __float_as_uint(v);
  return (u16)((x + 0x7fff + ((x >> 16) & 1)) >> 16);
}
// runtime-dtype INPUT load: fz=1 -> fp32 buffers, fz=0 -> bf16 buffers
__device__ __forceinline__ float ldf(const void* p, int idx, int fz) {
  if (fz) return ((const float*)p)[idx];
  return b2f(((const u16*)p)[idx]);
}
__device__ __forceinline__ void stf(void* p, int idx, int fz, float v) {
  if (fz) { ((float*)p)[idx] = v; return; }
  ((u16*)p)[idx] = f2b(v);
}

// ---------------- dtype detector: read W1 as bf16; fp32 data -> wild exponents
__global__ void k_detect(const u16* __restrict__ w, int* __restrict__ flag) {
  int t = threadIdx.x;
  int wild = 0;
  for (int j = t; j < 512; j += 64) {
    float a = fabsf(b2f(w[j]));
    if (!(a < 1e4f)) wild++;
  }
  #pragma unroll
  for (int off = 32; off; off >>= 1) wild += __shfl_xor(wild, off);
  if (t == 0) *flag = (wild > 16) ? 1 : 0;   // 1 => inputs are float32
}

// ---------------- prep: A_node = concat(cont, shape_emb, op_emb) @ W1[:121] + b1
__global__ void k_prep(const void* __restrict__ node_feat, const int* __restrict__ opcode,
                       const void* __restrict__ op_emb, const void* __restrict__ shape_emb,
                       const void* __restrict__ W1, const void* __restrict__ b1,
                       const int* __restrict__ dflag, float* __restrict__ A_node) {
  __shared__ float xn[128];
  int fz = *dflag;
  int i = blockIdx.x, t = threadIdx.x;
  float v = 0.f;
  if (t < NFD) {
    v = ldf(node_feat, i*NFROW + t, fz);
  } else if (t < NFD + SEDIM) {
    int st = (int)ldf(node_feat, i*NFROW + NFD, fz);
    st = min(max(st, 0), N_SHAPE_GUARD);
    v = ldf(shape_emb, st*SEDIM + (t - NFD), fz);
  } else if (t < XND) {
    int oc = min(max(opcode[i], 0), 119);
    v = ldf(op_emb, oc*OEDIM + (t - NFD - SEDIM), fz);
  }
  xn[t] = v;
  __syncthreads();
  float acc = ldf(b1, t, fz);
  for (int k = 0; k < XND; k++) acc += xn[k] * ldf(W1, k*128 + t, fz);
  A_node[i*128 + t] = acc;
}

// ---------------- C_cfg = config_feat @ W1[121:145]   (10000 x 128)
__global__ void k_cfg(const void* __restrict__ cfg, const void* __restrict__ W1,
                      const int* __restrict__ dflag, float* __restrict__ C_cfg) {
  int fz = *dflag;
  int r = blockIdx.x, t = threadIdx.x;
  __shared__ float cs[CFD];
  if (t < CFD) cs[t] = ldf(cfg, r*CFD + t, fz);
  __syncthreads();
  float acc = 0.f;
  for (int k = 0; k < CFD; k++) acc += cs[k] * ldf(W1, (XND + k)*128 + t, fz);
  C_cfg[r*128 + t] = acc;
}

// ---------------- pack weights to bf16 TRANSPOSED (n*K+k): MFMA B-operand layout
__global__ void k_wpackT(const void* __restrict__ W2,
                         const void* __restrict__ Wl0, const void* __restrict__ Wr0,
                         const void* __restrict__ Wl1, const void* __restrict__ Wr1,
                         const void* __restrict__ Wl2, const void* __restrict__ Wr2,
                         const int* __restrict__ dflag,
                         u16* __restrict__ W2t, u16* __restrict__ Wc0t,
                         u16* __restrict__ Wc1t, u16* __restrict__ Wc2t) {
  int fz = *dflag;
  int idx = blockIdx.x * 256 + threadIdx.x;
  if (idx < 16384) {           // W2t[n*128+k] = W2[k*128+n]
    int n = idx >> 7, k = idx & 127;
    W2t[idx] = f2b(ldf(W2, k*128 + n, fz)); return;
  }
  idx -= 16384;
  if (idx < 16384) {           // Wc0t[n*128+k]: n<64 -> Wl0[k*64+n] else Wr0[k*64+n-64]
    int n = idx >> 7, k = idx & 127;
    float v = (n < 64) ? ldf(Wl0, k*64 + n, fz) : ldf(Wr0, k*64 + n - 64, fz);
    Wc0t[idx] = f2b(v); return;
  }
  idx -= 16384;
  if (idx < 8192) {            // Wc1t[n*64+k]
    int n = idx >> 6, k = idx & 63;
    float v = (n < 64) ? ldf(Wl1, k*64 + n, fz) : ldf(Wr1, k*64 + n - 64, fz);
    Wc1t[idx] = f2b(v); return;
  }
  idx -= 8192;
  if (idx < 8192) {            // Wc2t[n*64+k]
    int n = idx >> 6, k = idx & 63;
    float v = (n < 64) ? ldf(Wl2, k*64 + n, fz) : ldf(Wr2, k*64 + n - 64, fz);
    Wc2t[idx] = f2b(v); return;
  }
}

// ---------------- build CSR (in-edges per dst) + degree
__global__ void k_csr(const int* __restrict__ edge_index, int* __restrict__ offs,
                      int* __restrict__ srcl, float* __restrict__ deg) {
  __shared__ int cnt[NN];
  __shared__ int offl[NN + 1];
  int t = threadIdx.x;
  for (int i = t; i < NN; i += 256) cnt[i] = 0;
  __syncthreads();
  for (int e = t; e < EE; e += 256) {
    int d = edge_index[EE + e] & 511; if (d < NN) atomicAdd(&cnt[d], 1);
  }
  __syncthreads();
  if (t == 0) {
    int s = 0;
    for (int i = 0; i < NN; i++) { offl[i] = s; s += cnt[i]; }
    offl[NN] = s;
  }
  __syncthreads();
  for (int i = t; i < NN; i += 256) { deg[i] = (float)cnt[i]; cnt[i] = offl[i]; }
  for (int i = t; i < NN + 1; i += 256) offs[i] = offl[i];
  __syncthreads();
  for (int e = t; e < EE; e += 256) {
    int d = edge_index[EE + e] & 511;
    if (d < NN) {
      int p = atomicAdd(&cnt[d], 1);
      srcl[p] = min(max(edge_index[e], 0), NN - 1);
    }
  }
}

// ---------------- X1 = relu(A_node[i] + C_cfg[batch[i],c])  -> bf16 (the W1 join)
__global__ __launch_bounds__(256) void k_build(
    const float* __restrict__ A_node, const float* __restrict__ C_cfg,
    const int* __restrict__ batch, u16* __restrict__ X1) {
  int tid = blockIdx.x * 256 + threadIdx.x;   // 12.8M threads: 4 k per thread
  int r = tid >> 5;
  int kq = (tid & 31) << 2;
  int i = r / NC, c = r - i * NC;
  int b = batch[i] % NB;
  float4 a  = reinterpret_cast<const float4*>(A_node)[i*32 + (kq >> 2)];
  float4 cf = reinterpret_cast<const float4*>(C_cfg)[(b*NC + c)*32 + (kq >> 2)];
  ushort4 st;
  st.x = f2b(fmaxf(a.x + cf.x, 0.f));
  st.y = f2b(fmaxf(a.y + cf.y, 0.f));
  st.z = f2b(fmaxf(a.z + cf.z, 0.f));
  st.w = f2b(fmaxf(a.w + cf.w, 0.f));
  *reinterpret_cast<ushort4*>(X1 + (size_t)r*128 + kq) = st;
}

// ---------------- MFMA GEMM: Out(M x 128) = A(M x K)bf16 @ Wt(128 x K)^T bf16
// fp32 accumulate in VGPRs. No LDS: A-frags and B-frags loaded directly from
// global (A each elem once, 64B-line coalesced via quads; Wt is L1-hot).
// In-place safe (In==Out): each wave reads only its own 32 rows, all reads
// complete (data-dep on mfma) before epilogue stores; waves own disjoint rows.
// Fragment layouts (verified, guide §3): A[m=lane&15][k=quad*8+j],
// B[n=lane&15][k=quad*8+j] (from transposed Wt), D: col=lane&15, row=quad*4+reg.
template<int K, bool BIASRELU>
__global__ __launch_bounds__(256) void k_mgemm(
    const u16* In, const u16* __restrict__ Wt, const void* __restrict__ bias,
    const int* __restrict__ dflag, u16* Out) {
  int w = threadIdx.x >> 6;          // wave 0..3
  int l = threadIdx.x & 63;
  int m_lane = l & 15, quad = l >> 4;
  size_t row_base = (size_t)blockIdx.x * 128 + w * 32;

  f32x4 acc[2][8] = {};
  const int KT = K / 32;
  #pragma unroll
  for (int kt = 0; kt < KT; kt++) {
    int ko = kt*32 + quad*8;
    bf16x8 a0 = *reinterpret_cast<const bf16x8*>(In + (row_base + m_lane)*K + ko);
    bf16x8 a1 = *reinterpret_cast<const bf16x8*>(In + (row_base + 16 + m_lane)*K + ko);
    #pragma unroll
    for (int nt = 0; nt < 8; nt++) {
      bf16x8 b = *reinterpret_cast<const bf16x8*>(Wt + (nt*16 + m_lane)*K + ko);
      acc[0][nt] = __builtin_amdgcn_mfma_f32_16x16x32_bf16(a0, b, acc[0][nt], 0, 0, 0);
      acc[1][nt] = __builtin_amdgcn_mfma_f32_16x16x32_bf16(a1, b, acc[1][nt], 0, 0, 0);
    }
  }

  int fz = 0;
  if (BIASRELU) fz = *dflag;
  #pragma unroll
  for (int nt = 0; nt < 8; nt++) {
    int col = nt*16 + m_lane;
    float bv = 0.f;
    if (BIASRELU) bv = ldf(bias, col, fz);
    #pragma unroll
    for (int mt = 0; mt < 2; mt++) {
      #pragma unroll
      for (int rg = 0; rg < 4; rg++) {
        float v = acc[mt][nt][rg];
        if (BIASRELU) v = fmaxf(v + bv, 0.f);
        size_t row = row_base + mt*16 + quad*4 + rg;
        Out[row*128 + col] = f2b(v);
      }
    }
  }
}

// ---------------- SAGE combine: x_next = relu(y + (sum_z over in-edges)/max(deg,1) + bg)
// yz: row (i*NC+c)*128, y at [0:64], z at [64:128]; xout row stride 64 (bf16)
__global__ __launch_bounds__(256) void k_agg(
    const u16* __restrict__ yz, const int* __restrict__ offs, const int* __restrict__ srcl,
    const float* __restrict__ deg, const void* __restrict__ bg,
    const int* __restrict__ dflag, u16* __restrict__ xout) {
  int fz = *dflag;
  int blk = blockIdx.x;
  int i = blk / (NC/4), cb = blk % (NC/4);
  int t = threadIdx.x, h = t & 63;
  int c = cb*4 + (t >> 6);
  int o0 = offs[i], o1 = offs[i + 1];
  float acc = 0.f;
  for (int e = o0; e < o1; e++) {
    int s = srcl[e];
    acc += b2f(yz[((size_t)s*NC + c)*128 + 64 + h]);
  }
  float d = fmaxf(deg[i], 1.f);
  float y = b2f(yz[((size_t)i*NC + c)*128 + h]);
  float v = y + acc / d + ldf(bg, h, fz);
  xout[((size_t)i*NC + c)*64 + h] = f2b(fmaxf(v, 0.f));
}

// ---------------- pool (max + mean over 40 nodes) -> L2 norm -> MLP head
// output dtype follows detected input dtype (fz=1 -> fp32, fz=0 -> bf16)
__global__ __launch_bounds__(256) void k_pool(
    const u16* __restrict__ x, const void* __restrict__ Wp1, const void* __restrict__ bp1,
    const void* __restrict__ Wp2, const void* __restrict__ bp2,
    const int* __restrict__ dflag, void* __restrict__ out) {
  int fz = *dflag;
  int b = blockIdx.x / (NC/4);
  int cb = blockIdx.x % (NC/4);
  int t = threadIdx.x;
  int h = t & 63;
  int w = t >> 6;                 // one wave = one config
  int c = cb*4 + w;
  __shared__ float wp1[64*32];
  __shared__ float bp1s[32], wp2s[32];
  __shared__ float xs[4][64];
  for (int f = t; f < 2048; f += 256) wp1[f] = ldf(Wp1, f, fz);
  if (t < 32) { bp1s[t] = ldf(bp1, t, fz); wp2s[t] = ldf(Wp2, t, fz); }
  float mx = -3.0e38f, sm = 0.f;
  for (int j = 0; j < 40; j++) {
    float v = b2f(x[((size_t)(b*40 + j)*NC + c)*64 + h]);
    mx = fmaxf(mx, v); sm += v;
  }
  float g = mx + sm * (1.f / 40.f);
  float sq = g * g;
  #pragma unroll
  for (int off = 32; off; off >>= 1) sq += __shfl_xor(sq, off);
  float gn = g * rsqrtf(sq);
  xs[w][h] = gn;
  __syncthreads();
  int j32 = h & 31;
  float hj = bp1s[j32];
  const float* xr = xs[w];
  for (int k = 0; k < 64; k++) hj += xr[k] * wp1[k*32 + j32];
  hj = fmaxf(hj, 0.f);
  float contrib = hj * wp2s[j32];   // lanes 0-31 and 32-63 duplicate -> sum/2
  #pragma unroll
  for (int off = 32; off; off >>= 1) contrib += __shfl_xor(contrib, off);
  if (h == 0) stf(out, b*NC + c, fz, contrib * 0.5f + ldf(bp2, 0, fz));
}

extern "C" void kernel_launch(void* const* d_in, const int* in_sizes, int n_in,
                              void* d_out, int out_size, void* d_ws, size_t ws_size,
                              hipStream_t stream) {
  const void* node_feat   = d_in[0];
  const int*  node_opcode = (const int*)d_in[1];
  const void* config_feat = d_in[2];
  const int*  edge_index  = (const int*)d_in[3];
  const int*  batch       = (const int*)d_in[4];
  const void* op_emb      = d_in[5];
  const void* shape_emb   = d_in[6];
  const void* W1  = d_in[7];
  const void* b1  = d_in[8];
  const void* W2  = d_in[9];
  const void* b2  = d_in[10];
  const void* Wl0 = d_in[11];
  const void* Wr0 = d_in[12];
  const void* bg0 = d_in[13];
  const void* Wl1 = d_in[14];
  const void* Wr1 = d_in[15];
  const void* bg1 = d_in[16];
  const void* Wl2 = d_in[17];
  const void* Wr2 = d_in[18];
  const void* bg2 = d_in[19];
  const void* Wp1 = d_in[20];
  const void* bp1 = d_in[21];
  const void* Wp2 = d_in[22];
  const void* bp2 = d_in[23];

  // workspace ~159 MB (known-safe; 313 MB faulted in round 2)
  char* p = (char*)d_ws;
  int*   flag   = (int*)p;   p += 256;
  float* A_node = (float*)p; p += 400*128*4;
  float* C_cfg  = (float*)p; p += 10000*128*4;
  u16*   W2t    = (u16*)p;   p += 128*128*2;
  u16*   Wc0t   = (u16*)p;   p += 128*128*2;
  u16*   Wc1t   = (u16*)p;   p += 128*64*2;
  u16*   Wc2t   = (u16*)p;   p += 128*64*2;
  int*   offs   = (int*)p;   p += 2048;
  int*   srcl   = (int*)p;   p += 4096;
  float* deg    = (float*)p; p += 2048;
  u16*   BIG    = (u16*)p;   p += (size_t)400*1000*128*2;   // X1/X2/[y|z] (in-place), bf16
  u16*   X      = (u16*)p;   p += (size_t)400*1000*64*2;    // sage outputs, bf16

  k_detect<<<dim3(1), dim3(64), 0, stream>>>((const u16*)W1, flag);
  k_prep<<<dim3(400), dim3(128), 0, stream>>>(node_feat, node_opcode, op_emb, shape_emb, W1, b1, flag, A_node);
  k_cfg<<<dim3(10000), dim3(128), 0, stream>>>(config_feat, W1, flag, C_cfg);
  k_wpackT<<<dim3(192), dim3(256), 0, stream>>>(W2, Wl0, Wr0, Wl1, Wr1, Wl2, Wr2, flag, W2t, Wc0t, Wc1t, Wc2t);
  k_csr<<<dim3(1), dim3(256), 0, stream>>>(edge_index, offs, srcl, deg);

  // X1 = relu(A_node + C_cfg[batch])                      -> BIG (400k x 128 bf16)
  k_build<<<dim3(50000), dim3(256), 0, stream>>>(A_node, C_cfg, batch, BIG);
  // X2 = relu(X1 @ W2 + b2)                               -> BIG (in-place)
  k_mgemm<128, true><<<dim3(3125), dim3(256), 0, stream>>>(BIG, W2t, b2, flag, BIG);
  // sage0: [y|z] = X2 @ [Wl0|Wr0]                         -> BIG (in-place)
  k_mgemm<128, false><<<dim3(3125), dim3(256), 0, stream>>>(BIG, Wc0t, nullptr, flag, BIG);
  k_agg<<<dim3(100000), dim3(256), 0, stream>>>(BIG, offs, srcl, deg, bg0, flag, X);
  // sage1
  k_mgemm<64, false><<<dim3(3125), dim3(256), 0, stream>>>(X, Wc1t, nullptr, flag, BIG);
  k_agg<<<dim3(100000), dim3(256), 0, stream>>>(BIG, offs, srcl, deg, bg1, flag, X);
  // sage2
  k_mgemm<64, false><<<dim3(3125), dim3(256), 0, stream>>>(X, Wc2t, nullptr, flag, BIG);
  k_agg<<<dim3(100000), dim3(256), 0, stream>>>(BIG, offs, srcl, deg, bg2, flag, X);
  // pool + norm + head
  k_pool<<<dim3(2500), dim3(256), 0, stream>>>(X, Wp1, bp1, Wp2, bp2, flag, d_out);
}

// Round 7
// 554.763 us; speedup vs baseline: 1.7823x; 1.1595x over previous
//
#include <hip/hip_runtime.h>
#include <hip/hip_bf16.h>

typedef unsigned short u16;
typedef short bf16x8 __attribute__((ext_vector_type(8)));   // 8 bf16 in 4 VGPRs
typedef float f32x4 __attribute__((ext_vector_type(4)));

#define NN 400
#define NB 10
#define NC 1000
#define CFD 24
#define NFD 85
#define NFROW 86
#define SEDIM 4
#define OEDIM 32
#define XND 121   // 85 + 4 + 32
#define EE 800
#define N_SHAPE_GUARD 7

// bf16 bit helpers (exact load; RNE store)
__device__ __forceinline__ float b2f(u16 u) { return __uint_as_float((unsigned)u << 16); }
__device__ __forceinline__ u16 f2b(float v) {
  unsigned x = __float_as_uint(v);
  return (u16)((x + 0x7fff + ((x >> 16) & 1)) >> 16);
}
// runtime-dtype INPUT load: fz=1 -> fp32 buffers, fz=0 -> bf16 buffers
__device__ __forceinline__ float ldf(const void* p, int idx, int fz) {
  if (fz) return ((const float*)p)[idx];
  return b2f(((const u16*)p)[idx]);
}
__device__ __forceinline__ void stf(void* p, int idx, int fz, float v) {
  if (fz) { ((float*)p)[idx] = v; return; }
  ((u16*)p)[idx] = f2b(v);
}

// ---------------- dtype detector: read W1 as bf16; fp32 data -> wild exponents
__global__ void k_detect(const u16* __restrict__ w, int* __restrict__ flag) {
  int t = threadIdx.x;
  int wild = 0;
  for (int j = t; j < 512; j += 64) {
    float a = fabsf(b2f(w[j]));
    if (!(a < 1e4f)) wild++;
  }
  #pragma unroll
  for (int off = 32; off; off >>= 1) wild += __shfl_xor(wild, off);
  if (t == 0) *flag = (wild > 16) ? 1 : 0;   // 1 => inputs are float32
}

// ---------------- prep: A_node = concat(cont, shape_emb, op_emb) @ W1[:121] + b1
__global__ void k_prep(const void* __restrict__ node_feat, const int* __restrict__ opcode,
                       const void* __restrict__ op_emb, const void* __restrict__ shape_emb,
                       const void* __restrict__ W1, const void* __restrict__ b1,
                       const int* __restrict__ dflag, float* __restrict__ A_node) {
  __shared__ float xn[128];
  int fz = *dflag;
  int i = blockIdx.x, t = threadIdx.x;
  float v = 0.f;
  if (t < NFD) {
    v = ldf(node_feat, i*NFROW + t, fz);
  } else if (t < NFD + SEDIM) {
    int st = (int)ldf(node_feat, i*NFROW + NFD, fz);
    st = min(max(st, 0), N_SHAPE_GUARD);
    v = ldf(shape_emb, st*SEDIM + (t - NFD), fz);
  } else if (t < XND) {
    int oc = min(max(opcode[i], 0), 119);
    v = ldf(op_emb, oc*OEDIM + (t - NFD - SEDIM), fz);
  }
  xn[t] = v;
  __syncthreads();
  float acc = ldf(b1, t, fz);
  for (int k = 0; k < XND; k++) acc += xn[k] * ldf(W1, k*128 + t, fz);
  A_node[i*128 + t] = acc;
}

// ---------------- C_cfg = config_feat @ W1[121:145]   (10000 x 128)
__global__ void k_cfg(const void* __restrict__ cfg, const void* __restrict__ W1,
                      const int* __restrict__ dflag, float* __restrict__ C_cfg) {
  int fz = *dflag;
  int r = blockIdx.x, t = threadIdx.x;
  __shared__ float cs[CFD];
  if (t < CFD) cs[t] = ldf(cfg, r*CFD + t, fz);
  __syncthreads();
  float acc = 0.f;
  for (int k = 0; k < CFD; k++) acc += cs[k] * ldf(W1, (XND + k)*128 + t, fz);
  C_cfg[r*128 + t] = acc;
}

// ---------------- pack weights to bf16 TRANSPOSED (n*K+k): MFMA B-operand layout
__global__ void k_wpackT(const void* __restrict__ W2,
                         const void* __restrict__ Wl0, const void* __restrict__ Wr0,
                         const void* __restrict__ Wl1, const void* __restrict__ Wr1,
                         const void* __restrict__ Wl2, const void* __restrict__ Wr2,
                         const int* __restrict__ dflag,
                         u16* __restrict__ W2t, u16* __restrict__ Wc0t,
                         u16* __restrict__ Wc1t, u16* __restrict__ Wc2t) {
  int fz = *dflag;
  int idx = blockIdx.x * 256 + threadIdx.x;
  if (idx < 16384) {           // W2t[n*128+k] = W2[k*128+n]
    int n = idx >> 7, k = idx & 127;
    W2t[idx] = f2b(ldf(W2, k*128 + n, fz)); return;
  }
  idx -= 16384;
  if (idx < 16384) {           // Wc0t[n*128+k]: n<64 -> Wl0[k*64+n] else Wr0[k*64+n-64]
    int n = idx >> 7, k = idx & 127;
    float v = (n < 64) ? ldf(Wl0, k*64 + n, fz) : ldf(Wr0, k*64 + n - 64, fz);
    Wc0t[idx] = f2b(v); return;
  }
  idx -= 16384;
  if (idx < 8192) {            // Wc1t[n*64+k]
    int n = idx >> 6, k = idx & 63;
    float v = (n < 64) ? ldf(Wl1, k*64 + n, fz) : ldf(Wr1, k*64 + n - 64, fz);
    Wc1t[idx] = f2b(v); return;
  }
  idx -= 8192;
  if (idx < 8192) {            // Wc2t[n*64+k]
    int n = idx >> 6, k = idx & 63;
    float v = (n < 64) ? ldf(Wl2, k*64 + n, fz) : ldf(Wr2, k*64 + n - 64, fz);
    Wc2t[idx] = f2b(v); return;
  }
}

// ---------------- build CSR (in-edges per dst) + degree
__global__ void k_csr(const int* __restrict__ edge_index, int* __restrict__ offs,
                      int* __restrict__ srcl, float* __restrict__ deg) {
  __shared__ int cnt[NN];
  __shared__ int offl[NN + 1];
  int t = threadIdx.x;
  for (int i = t; i < NN; i += 256) cnt[i] = 0;
  __syncthreads();
  for (int e = t; e < EE; e += 256) {
    int d = edge_index[EE + e] & 511; if (d < NN) atomicAdd(&cnt[d], 1);
  }
  __syncthreads();
  if (t == 0) {
    int s = 0;
    for (int i = 0; i < NN; i++) { offl[i] = s; s += cnt[i]; }
    offl[NN] = s;
  }
  __syncthreads();
  for (int i = t; i < NN; i += 256) { deg[i] = (float)cnt[i]; cnt[i] = offl[i]; }
  for (int i = t; i < NN + 1; i += 256) offs[i] = offl[i];
  __syncthreads();
  for (int e = t; e < EE; e += 256) {
    int d = edge_index[EE + e] & 511;
    if (d < NN) {
      int p = atomicAdd(&cnt[d], 1);
      srcl[p] = min(max(edge_index[e], 0), NN - 1);
    }
  }
}

// ---------------- MFMA GEMM: Out(M x 128) = A(M x K)bf16 @ Wt(128 x K)^T bf16
// Latency plan: A-frags prefetched to VGPRs BEFORE the barrier (drained by the
// barrier's vmcnt); Wt staged in LDS (padded stride K+8 -> 2-way bank aliasing,
// free); inner loop = ds_read_b128 + mfma only (separate pipes).
// BUILD: A-frag = relu(A_node[i,k] + C_cfg[batch[i]*NC+c, k]), i=row/NC, c=row%NC
// (the factored-W1 early join; C_cfg is 5 MB -> L2/L3-hot, X1 never materialized).
// In-place safe (In==Out): all A reads complete before epilogue stores; waves own
// disjoint rows. Fragment layouts verified in rounds 5-6 (identical absmax).
template<int K, bool BUILD, bool BIASRELU>
__global__ __launch_bounds__(256) void k_mgemm(
    const u16* In, const u16* __restrict__ Wt,
    const float* __restrict__ A_node, const float* __restrict__ C_cfg,
    const int* __restrict__ batch,
    const void* __restrict__ bias, const int* __restrict__ dflag, u16* Out) {
  constexpr int KT = K / 32;
  constexpr int LROW = K + 8;            // padded LDS row stride (bf16 elems), 16B-aligned
  __shared__ __align__(16) u16 Blds[128 * LROW];
  int t = threadIdx.x;
  int w = t >> 6, l = t & 63;
  int m_lane = l & 15, quad = l >> 4;
  size_t row_base = (size_t)blockIdx.x * 128 + w * 32;

  // ---- prefetch A fragments into registers
  bf16x8 afr[2][KT];
  if (BUILD) {
    #pragma unroll
    for (int mt = 0; mt < 2; mt++) {
      int row = (int)row_base + mt*16 + m_lane;
      int i = row / NC, c = row - i*NC;
      int b = batch[i] % NB;
      const float* an = A_node + i*128;
      const float* cf = C_cfg + ((size_t)b*NC + c)*128;
      #pragma unroll
      for (int kt = 0; kt < KT; kt++) {
        int ko = kt*32 + quad*8;
        float4 a0 = *(const float4*)(an + ko);
        float4 a1 = *(const float4*)(an + ko + 4);
        float4 c0 = *(const float4*)(cf + ko);
        float4 c1 = *(const float4*)(cf + ko + 4);
        bf16x8 f;
        f[0] = (short)f2b(fmaxf(a0.x + c0.x, 0.f));
        f[1] = (short)f2b(fmaxf(a0.y + c0.y, 0.f));
        f[2] = (short)f2b(fmaxf(a0.z + c0.z, 0.f));
        f[3] = (short)f2b(fmaxf(a0.w + c0.w, 0.f));
        f[4] = (short)f2b(fmaxf(a1.x + c1.x, 0.f));
        f[5] = (short)f2b(fmaxf(a1.y + c1.y, 0.f));
        f[6] = (short)f2b(fmaxf(a1.z + c1.z, 0.f));
        f[7] = (short)f2b(fmaxf(a1.w + c1.w, 0.f));
        afr[mt][kt] = f;
      }
    }
  } else {
    #pragma unroll
    for (int mt = 0; mt < 2; mt++) {
      #pragma unroll
      for (int kt = 0; kt < KT; kt++) {
        int ko = kt*32 + quad*8;
        afr[mt][kt] = *reinterpret_cast<const bf16x8*>(In + (row_base + mt*16 + m_lane)*K + ko);
      }
    }
  }

  // ---- stage Wt (128 x K, row-major) into padded LDS
  for (int idx = t; idx < 128*K/8; idx += 256) {
    int n = idx / (K/8), ch = idx % (K/8);
    uint4 v = reinterpret_cast<const uint4*>(Wt)[idx];
    *reinterpret_cast<uint4*>(&Blds[n*LROW + ch*8]) = v;
  }
  __syncthreads();

  // ---- K-loop: ds_read B-frags + MFMA (no global traffic)
  f32x4 acc[2][8] = {};
  #pragma unroll
  for (int kt = 0; kt < KT; kt++) {
    int ko = kt*32 + quad*8;
    #pragma unroll
    for (int nt = 0; nt < 8; nt++) {
      bf16x8 b = *reinterpret_cast<const bf16x8*>(&Blds[(nt*16 + m_lane)*LROW + ko]);
      acc[0][nt] = __builtin_amdgcn_mfma_f32_16x16x32_bf16(afr[0][kt], b, acc[0][nt], 0, 0, 0);
      acc[1][nt] = __builtin_amdgcn_mfma_f32_16x16x32_bf16(afr[1][kt], b, acc[1][nt], 0, 0, 0);
    }
  }

  // ---- epilogue: D layout col=lane&15, row=quad*4+reg
  int fz = 0;
  if (BIASRELU) fz = *dflag;
  #pragma unroll
  for (int nt = 0; nt < 8; nt++) {
    int col = nt*16 + m_lane;
    float bv = 0.f;
    if (BIASRELU) bv = ldf(bias, col, fz);
    #pragma unroll
    for (int mt = 0; mt < 2; mt++) {
      #pragma unroll
      for (int rg = 0; rg < 4; rg++) {
        float v = acc[mt][nt][rg];
        if (BIASRELU) v = fmaxf(v + bv, 0.f);
        size_t row = row_base + mt*16 + quad*4 + rg;
        Out[row*128 + col] = f2b(v);
      }
    }
  }
}

// ---------------- SAGE combine: x_next = relu(y + (sum_z over in-edges)/max(deg,1) + bg)
// yz: row (i*NC+c)*128, y at [0:64], z at [64:128]; xout row stride 64 (bf16)
__global__ __launch_bounds__(256) void k_agg(
    const u16* __restrict__ yz, const int* __restrict__ offs, const int* __restrict__ srcl,
    const float* __restrict__ deg, const void* __restrict__ bg,
    const int* __restrict__ dflag, u16* __restrict__ xout) {
  int fz = *dflag;
  int blk = blockIdx.x;
  int i = blk / (NC/4), cb = blk % (NC/4);
  int t = threadIdx.x, h = t & 63;
  int c = cb*4 + (t >> 6);
  int o0 = offs[i], o1 = offs[i + 1];
  float acc = 0.f;
  for (int e = o0; e < o1; e++) {
    int s = srcl[e];
    acc += b2f(yz[((size_t)s*NC + c)*128 + 64 + h]);
  }
  float d = fmaxf(deg[i], 1.f);
  float y = b2f(yz[((size_t)i*NC + c)*128 + h]);
  float v = y + acc / d + ldf(bg, h, fz);
  xout[((size_t)i*NC + c)*64 + h] = f2b(fmaxf(v, 0.f));
}

// ---------------- pool (max + mean over 40 nodes) -> L2 norm -> MLP head
// output dtype follows detected input dtype (fz=1 -> fp32, fz=0 -> bf16)
__global__ __launch_bounds__(256) void k_pool(
    const u16* __restrict__ x, const void* __restrict__ Wp1, const void* __restrict__ bp1,
    const void* __restrict__ Wp2, const void* __restrict__ bp2,
    const int* __restrict__ dflag, void* __restrict__ out) {
  int fz = *dflag;
  int b = blockIdx.x / (NC/4);
  int cb = blockIdx.x % (NC/4);
  int t = threadIdx.x;
  int h = t & 63;
  int w = t >> 6;                 // one wave = one config
  int c = cb*4 + w;
  __shared__ float wp1[64*32];
  __shared__ float bp1s[32], wp2s[32];
  __shared__ float xs[4][64];
  for (int f = t; f < 2048; f += 256) wp1[f] = ldf(Wp1, f, fz);
  if (t < 32) { bp1s[t] = ldf(bp1, t, fz); wp2s[t] = ldf(Wp2, t, fz); }
  float mx = -3.0e38f, sm = 0.f;
  for (int j = 0; j < 40; j++) {
    float v = b2f(x[((size_t)(b*40 + j)*NC + c)*64 + h]);
    mx = fmaxf(mx, v); sm += v;
  }
  float g = mx + sm * (1.f / 40.f);
  float sq = g * g;
  #pragma unroll
  for (int off = 32; off; off >>= 1) sq += __shfl_xor(sq, off);
  float gn = g * rsqrtf(sq);
  xs[w][h] = gn;
  __syncthreads();
  int j32 = h & 31;
  float hj = bp1s[j32];
  const float* xr = xs[w];
  for (int k = 0; k < 64; k++) hj += xr[k] * wp1[k*32 + j32];
  hj = fmaxf(hj, 0.f);
  float contrib = hj * wp2s[j32];   // lanes 0-31 and 32-63 duplicate -> sum/2
  #pragma unroll
  for (int off = 32; off; off >>= 1) contrib += __shfl_xor(contrib, off);
  if (h == 0) stf(out, b*NC + c, fz, contrib * 0.5f + ldf(bp2, 0, fz));
}

extern "C" void kernel_launch(void* const* d_in, const int* in_sizes, int n_in,
                              void* d_out, int out_size, void* d_ws, size_t ws_size,
                              hipStream_t stream) {
  const void* node_feat   = d_in[0];
  const int*  node_opcode = (const int*)d_in[1];
  const void* config_feat = d_in[2];
  const int*  edge_index  = (const int*)d_in[3];
  const int*  batch       = (const int*)d_in[4];
  const void* op_emb      = d_in[5];
  const void* shape_emb   = d_in[6];
  const void* W1  = d_in[7];
  const void* b1  = d_in[8];
  const void* W2  = d_in[9];
  const void* b2  = d_in[10];
  const void* Wl0 = d_in[11];
  const void* Wr0 = d_in[12];
  const void* bg0 = d_in[13];
  const void* Wl1 = d_in[14];
  const void* Wr1 = d_in[15];
  const void* bg1 = d_in[16];
  const void* Wl2 = d_in[17];
  const void* Wr2 = d_in[18];
  const void* bg2 = d_in[19];
  const void* Wp1 = d_in[20];
  const void* bp1 = d_in[21];
  const void* Wp2 = d_in[22];
  const void* bp2 = d_in[23];

  // workspace ~159 MB (known-safe; 313 MB faulted in round 2)
  char* p = (char*)d_ws;
  int*   flag   = (int*)p;   p += 256;
  float* A_node = (float*)p; p += 400*128*4;
  float* C_cfg  = (float*)p; p += 10000*128*4;
  u16*   W2t    = (u16*)p;   p += 128*128*2;
  u16*   Wc0t   = (u16*)p;   p += 128*128*2;
  u16*   Wc1t   = (u16*)p;   p += 128*64*2;
  u16*   Wc2t   = (u16*)p;   p += 128*64*2;
  int*   offs   = (int*)p;   p += 2048;
  int*   srcl   = (int*)p;   p += 4096;
  float* deg    = (float*)p; p += 2048;
  u16*   BIG    = (u16*)p;   p += (size_t)400*1000*128*2;   // X2/[y|z] (in-place), bf16
  u16*   X      = (u16*)p;   p += (size_t)400*1000*64*2;    // sage outputs, bf16

  k_detect<<<dim3(1), dim3(64), 0, stream>>>((const u16*)W1, flag);
  k_prep<<<dim3(400), dim3(128), 0, stream>>>(node_feat, node_opcode, op_emb, shape_emb, W1, b1, flag, A_node);
  k_cfg<<<dim3(10000), dim3(128), 0, stream>>>(config_feat, W1, flag, C_cfg);
  k_wpackT<<<dim3(192), dim3(256), 0, stream>>>(W2, Wl0, Wr0, Wl1, Wr1, Wl2, Wr2, flag, W2t, Wc0t, Wc1t, Wc2t);
  k_csr<<<dim3(1), dim3(256), 0, stream>>>(edge_index, offs, srcl, deg);

  // X2 = relu(relu(A_node + C_cfg[batch]) @ W2 + b2)      -> BIG  (fused build)
  k_mgemm<128, true, true><<<dim3(3125), dim3(256), 0, stream>>>(nullptr, W2t, A_node, C_cfg, batch, b2, flag, BIG);
  // sage0: [y|z] = X2 @ [Wl0|Wr0]                         -> BIG (in-place)
  k_mgemm<128, false, false><<<dim3(3125), dim3(256), 0, stream>>>(BIG, Wc0t, nullptr, nullptr, nullptr, nullptr, flag, BIG);
  k_agg<<<dim3(100000), dim3(256), 0, stream>>>(BIG, offs, srcl, deg, bg0, flag, X);
  // sage1
  k_mgemm<64, false, false><<<dim3(3125), dim3(256), 0, stream>>>(X, Wc1t, nullptr, nullptr, nullptr, nullptr, flag, BIG);
  k_agg<<<dim3(100000), dim3(256), 0, stream>>>(BIG, offs, srcl, deg, bg1, flag, X);
  // sage2
  k_mgemm<64, false, false><<<dim3(3125), dim3(256), 0, stream>>>(X, Wc2t, nullptr, nullptr, nullptr, nullptr, flag, BIG);
  k_agg<<<dim3(100000), dim3(256), 0, stream>>>(BIG, offs, srcl, deg, bg2, flag, X);
  // pool + norm + head
  k_pool<<<dim3(2500), dim3(256), 0, stream>>>(X, Wp1, bp1, Wp2, bp2, flag, d_out);
}

// Round 8
// 480.960 us; speedup vs baseline: 2.0558x; 1.1535x over previous
//
#include <hip/hip_runtime.h>
#include <hip/hip_bf16.h>

typedef unsigned short u16;
typedef short bf16x8 __attribute__((ext_vector_type(8)));   // 8 bf16 in 4 VGPRs
typedef float f32x4 __attribute__((ext_vector_type(4)));

#define NN 400
#define NB 10
#define NC 1000
#define CFD 24
#define NFD 85
#define NFROW 86
#define SEDIM 4
#define OEDIM 32
#define XND 121   // 85 + 4 + 32
#define EE 800
#define N_SHAPE_GUARD 7

// bf16 bit helpers (exact load; RNE store)
__device__ __forceinline__ float b2f(u16 u) { return __uint_as_float((unsigned)u << 16); }
__device__ __forceinline__ u16 f2b(float v) {
  unsigned x = __float_as_uint(v);
  return (u16)((x + 0x7fff + ((x >> 16) & 1)) >> 16);
}
__device__ __forceinline__ unsigned pk2(float a, float b) {
  return (unsigned)f2b(a) | ((unsigned)f2b(b) << 16);
}
// runtime-dtype INPUT load: fz=1 -> fp32 buffers, fz=0 -> bf16 buffers
__device__ __forceinline__ float ldf(const void* p, int idx, int fz) {
  if (fz) return ((const float*)p)[idx];
  return b2f(((const u16*)p)[idx]);
}
__device__ __forceinline__ void stf(void* p, int idx, int fz, float v) {
  if (fz) { ((float*)p)[idx] = v; return; }
  ((u16*)p)[idx] = f2b(v);
}

// ---------------- dtype detector: read W1 as bf16; fp32 data -> wild exponents
__global__ void k_detect(const u16* __restrict__ w, int* __restrict__ flag) {
  int t = threadIdx.x;
  int wild = 0;
  for (int j = t; j < 512; j += 64) {
    float a = fabsf(b2f(w[j]));
    if (!(a < 1e4f)) wild++;
  }
  #pragma unroll
  for (int off = 32; off; off >>= 1) wild += __shfl_xor(wild, off);
  if (t == 0) *flag = (wild > 16) ? 1 : 0;   // 1 => inputs are float32
}

// ---------------- prep: A_node = concat(cont, shape_emb, op_emb) @ W1[:121] + b1
__global__ void k_prep(const void* __restrict__ node_feat, const int* __restrict__ opcode,
                       const void* __restrict__ op_emb, const void* __restrict__ shape_emb,
                       const void* __restrict__ W1, const void* __restrict__ b1,
                       const int* __restrict__ dflag, float* __restrict__ A_node) {
  __shared__ float xn[128];
  int fz = *dflag;
  int i = blockIdx.x, t = threadIdx.x;
  float v = 0.f;
  if (t < NFD) {
    v = ldf(node_feat, i*NFROW + t, fz);
  } else if (t < NFD + SEDIM) {
    int st = (int)ldf(node_feat, i*NFROW + NFD, fz);
    st = min(max(st, 0), N_SHAPE_GUARD);
    v = ldf(shape_emb, st*SEDIM + (t - NFD), fz);
  } else if (t < XND) {
    int oc = min(max(opcode[i], 0), 119);
    v = ldf(op_emb, oc*OEDIM + (t - NFD - SEDIM), fz);
  }
  xn[t] = v;
  __syncthreads();
  float acc = ldf(b1, t, fz);
  for (int k = 0; k < XND; k++) acc += xn[k] * ldf(W1, k*128 + t, fz);
  A_node[i*128 + t] = acc;
}

// ---------------- C_cfg = config_feat @ W1[121:145]   (10000 x 128)
__global__ void k_cfg(const void* __restrict__ cfg, const void* __restrict__ W1,
                      const int* __restrict__ dflag, float* __restrict__ C_cfg) {
  int fz = *dflag;
  int r = blockIdx.x, t = threadIdx.x;
  __shared__ float cs[CFD];
  if (t < CFD) cs[t] = ldf(cfg, r*CFD + t, fz);
  __syncthreads();
  float acc = 0.f;
  for (int k = 0; k < CFD; k++) acc += cs[k] * ldf(W1, (XND + k)*128 + t, fz);
  C_cfg[r*128 + t] = acc;
}

// ---------------- pack weights to bf16 TRANSPOSED (n*K+k): MFMA operand layout
__global__ void k_wpackT(const void* __restrict__ W2,
                         const void* __restrict__ Wl0, const void* __restrict__ Wr0,
                         const void* __restrict__ Wl1, const void* __restrict__ Wr1,
                         const void* __restrict__ Wl2, const void* __restrict__ Wr2,
                         const int* __restrict__ dflag,
                         u16* __restrict__ W2t, u16* __restrict__ Wc0t,
                         u16* __restrict__ Wc1t, u16* __restrict__ Wc2t) {
  int fz = *dflag;
  int idx = blockIdx.x * 256 + threadIdx.x;
  if (idx < 16384) {           // W2t[n*128+k] = W2[k*128+n]
    int n = idx >> 7, k = idx & 127;
    W2t[idx] = f2b(ldf(W2, k*128 + n, fz)); return;
  }
  idx -= 16384;
  if (idx < 16384) {           // Wc0t[n*128+k]
    int n = idx >> 7, k = idx & 127;
    float v = (n < 64) ? ldf(Wl0, k*64 + n, fz) : ldf(Wr0, k*64 + n - 64, fz);
    Wc0t[idx] = f2b(v); return;
  }
  idx -= 16384;
  if (idx < 8192) {            // Wc1t[n*64+k]
    int n = idx >> 6, k = idx & 63;
    float v = (n < 64) ? ldf(Wl1, k*64 + n, fz) : ldf(Wr1, k*64 + n - 64, fz);
    Wc1t[idx] = f2b(v); return;
  }
  idx -= 8192;
  if (idx < 8192) {            // Wc2t[n*64+k]
    int n = idx >> 6, k = idx & 63;
    float v = (n < 64) ? ldf(Wl2, k*64 + n, fz) : ldf(Wr2, k*64 + n - 64, fz);
    Wc2t[idx] = f2b(v); return;
  }
}

// ---------------- build CSR (in-edges per dst) + degree
__global__ void k_csr(const int* __restrict__ edge_index, int* __restrict__ offs,
                      int* __restrict__ srcl, float* __restrict__ deg) {
  __shared__ int cnt[NN];
  __shared__ int offl[NN + 1];
  int t = threadIdx.x;
  for (int i = t; i < NN; i += 256) cnt[i] = 0;
  __syncthreads();
  for (int e = t; e < EE; e += 256) {
    int d = edge_index[EE + e] & 511; if (d < NN) atomicAdd(&cnt[d], 1);
  }
  __syncthreads();
  if (t == 0) {
    int s = 0;
    for (int i = 0; i < NN; i++) { offl[i] = s; s += cnt[i]; }
    offl[NN] = s;
  }
  __syncthreads();
  for (int i = t; i < NN; i += 256) { deg[i] = (float)cnt[i]; cnt[i] = offl[i]; }
  for (int i = t; i < NN + 1; i += 256) offs[i] = offl[i];
  __syncthreads();
  for (int e = t; e < EE; e += 256) {
    int d = edge_index[EE + e] & 511;
    if (d < NN) {
      int p = atomicAdd(&cnt[d], 1);
      srcl[p] = min(max(edge_index[e], 0), NN - 1);
    }
  }
}

// ---------------- MFMA GEMM: Out(M x 128) = Acts(M x K) @ Wt(128 x K)^T, bf16
// OPERAND SWAP: MFMA A = weight frag (m-dim = 128 output ch, 8 m-tiles),
//               MFMA B = activation frag (n-dim = rows; wave owns 32 rows).
// => D row-axis (quad*4+reg) = output ch -> ushort4 vector stores.
// Weights in XOR-SWIZZLED LDS (chunk ^= row & (K/8-1)): ds_read_b128 lands
// 2 lanes/bank = free (r7's +8 pad was 4 banks -> 8-way conflict, 1.6M cycles).
// Acts/BUILD frags: 32 VGPRs, loaded before the barrier (latency overlapped).
// In-place safe (In==Out): block reads only its own 128 rows, all reads
// complete (MFMA data-dep) before epilogue stores.
template<int K, bool BUILD, bool BIASRELU>
__global__ __launch_bounds__(256) void k_mgemm(
    const u16* In, const u16* __restrict__ Wt,
    const float* __restrict__ A_node, const float* __restrict__ C_cfg,
    const int* __restrict__ batch,
    const void* __restrict__ bias, const int* __restrict__ dflag, u16* Out) {
  constexpr int KT = K / 32;           // MFMA k-steps
  constexpr int CH = K / 8;            // 16B chunks per weight row
  __shared__ __align__(16) u16 Wlds[128 * K];
  int t = threadIdx.x;
  int w = t >> 6, l = t & 63;
  int lm = l & 15, quad = l >> 4;
  size_t rb = (size_t)blockIdx.x * 128;   // block's first row
  int nrow0 = w * 32;                     // wave's rows within block

  // ---- B-frags (activations), 2 n-tiles x KT, into registers
  bf16x8 bfr[2][KT];
  if (BUILD) {
    #pragma unroll
    for (int nt = 0; nt < 2; nt++) {
      int row = (int)rb + nrow0 + nt*16 + lm;
      int i = row / NC, c = row - i*NC;
      int b = batch[i] % NB;
      const float* an = A_node + i*128;
      const float* cf = C_cfg + ((size_t)b*NC + c)*128;
      #pragma unroll
      for (int kt = 0; kt < KT; kt++) {
        int ko = kt*32 + quad*8;
        float4 a0 = *(const float4*)(an + ko);
        float4 a1 = *(const float4*)(an + ko + 4);
        float4 c0 = *(const float4*)(cf + ko);
        float4 c1 = *(const float4*)(cf + ko + 4);
        bf16x8 f;
        f[0] = (short)f2b(fmaxf(a0.x + c0.x, 0.f));
        f[1] = (short)f2b(fmaxf(a0.y + c0.y, 0.f));
        f[2] = (short)f2b(fmaxf(a0.z + c0.z, 0.f));
        f[3] = (short)f2b(fmaxf(a0.w + c0.w, 0.f));
        f[4] = (short)f2b(fmaxf(a1.x + c1.x, 0.f));
        f[5] = (short)f2b(fmaxf(a1.y + c1.y, 0.f));
        f[6] = (short)f2b(fmaxf(a1.z + c1.z, 0.f));
        f[7] = (short)f2b(fmaxf(a1.w + c1.w, 0.f));
        bfr[nt][kt] = f;
      }
    }
  } else {
    #pragma unroll
    for (int nt = 0; nt < 2; nt++) {
      #pragma unroll
      for (int kt = 0; kt < KT; kt++) {
        int ko = kt*32 + quad*8;
        bfr[nt][kt] = *reinterpret_cast<const bf16x8*>(In + (rb + nrow0 + nt*16 + lm)*K + ko);
      }
    }
  }

  // ---- stage weights (128 x K row-major) into XOR-swizzled LDS
  for (int idx = t; idx < 128 * CH; idx += 256) {
    int r = idx / CH, j = idx % CH;          // CH is power of 2 -> shifts
    uint4 v = reinterpret_cast<const uint4*>(Wt)[idx];
    *reinterpret_cast<uint4*>(&Wlds[(r*CH + (j ^ (r & (CH - 1)))) * 8]) = v;
  }
  __syncthreads();

  // ---- K-loop: swizzled ds_read A-frags (weights) + MFMA
  f32x4 acc[8][2] = {};
  #pragma unroll
  for (int kt = 0; kt < KT; kt++) {
    #pragma unroll
    for (int mt = 0; mt < 8; mt++) {
      int oc = mt*16 + lm;
      int ch = (kt*4 + quad) ^ (oc & (CH - 1));
      bf16x8 a = *reinterpret_cast<const bf16x8*>(&Wlds[(oc*CH + ch) * 8]);
      acc[mt][0] = __builtin_amdgcn_mfma_f32_16x16x32_bf16(a, bfr[0][kt], acc[mt][0], 0, 0, 0);
      acc[mt][1] = __builtin_amdgcn_mfma_f32_16x16x32_bf16(a, bfr[1][kt], acc[mt][1], 0, 0, 0);
    }
  }

  // ---- epilogue: D col = act-row-in-tile (lm), D row = oc-in-tile (quad*4+rg)
  int fz = 0;
  if (BIASRELU) fz = *dflag;
  #pragma unroll
  for (int mt = 0; mt < 8; mt++) {
    float bv[4] = {0.f, 0.f, 0.f, 0.f};
    if (BIASRELU) {
      #pragma unroll
      for (int rg = 0; rg < 4; rg++) bv[rg] = ldf(bias, mt*16 + quad*4 + rg, fz);
    }
    #pragma unroll
    for (int nt = 0; nt < 2; nt++) {
      size_t arow = rb + nrow0 + nt*16 + lm;
      ushort4 s;
      float v0 = acc[mt][nt][0], v1 = acc[mt][nt][1];
      float v2 = acc[mt][nt][2], v3 = acc[mt][nt][3];
      if (BIASRELU) {
        v0 = fmaxf(v0 + bv[0], 0.f); v1 = fmaxf(v1 + bv[1], 0.f);
        v2 = fmaxf(v2 + bv[2], 0.f); v3 = fmaxf(v3 + bv[3], 0.f);
      }
      s.x = f2b(v0); s.y = f2b(v1); s.z = f2b(v2); s.w = f2b(v3);
      *reinterpret_cast<ushort4*>(Out + arow*128 + mt*16 + quad*4) = s;
    }
  }
}

// ---------------- SAGE combine, vectorized: thread = (row, 8-channel octet)
// x_next = relu(y + (sum_z over in-edges)/max(deg,1) + bg); uint4 loads/stores
__global__ __launch_bounds__(256) void k_agg(
    const u16* __restrict__ yz, const int* __restrict__ offs, const int* __restrict__ srcl,
    const float* __restrict__ deg, const void* __restrict__ bg,
    const int* __restrict__ dflag, u16* __restrict__ xout) {
  int fz = *dflag;
  int g = blockIdx.x * 256 + threadIdx.x;    // 3.2M = 400k rows x 8 octets
  int o = g & 7;
  int row = g >> 3;
  int i = row / NC, c = row - i*NC;
  const uint4* yzv = reinterpret_cast<const uint4*>(yz);
  int o0 = offs[i], o1 = offs[i + 1];
  float a[8] = {0,0,0,0,0,0,0,0};
  for (int e = o0; e < o1; e++) {
    int s = srcl[e];
    uint4 zv = yzv[(size_t)(s*NC + c)*16 + 8 + o];
    a[0] += b2f((u16)(zv.x & 0xffff)); a[1] += b2f((u16)(zv.x >> 16));
    a[2] += b2f((u16)(zv.y & 0xffff)); a[3] += b2f((u16)(zv.y >> 16));
    a[4] += b2f((u16)(zv.z & 0xffff)); a[5] += b2f((u16)(zv.z >> 16));
    a[6] += b2f((u16)(zv.w & 0xffff)); a[7] += b2f((u16)(zv.w >> 16));
  }
  float rd = 1.f / fmaxf(deg[i], 1.f);
  uint4 yv = yzv[(size_t)row*16 + o];
  float y[8];
  y[0] = b2f((u16)(yv.x & 0xffff)); y[1] = b2f((u16)(yv.x >> 16));
  y[2] = b2f((u16)(yv.y & 0xffff)); y[3] = b2f((u16)(yv.y >> 16));
  y[4] = b2f((u16)(yv.z & 0xffff)); y[5] = b2f((u16)(yv.z >> 16));
  y[6] = b2f((u16)(yv.w & 0xffff)); y[7] = b2f((u16)(yv.w >> 16));
  float r[8];
  #pragma unroll
  for (int j = 0; j < 8; j++)
    r[j] = fmaxf(y[j] + a[j]*rd + ldf(bg, o*8 + j, fz), 0.f);
  uint4 s;
  s.x = pk2(r[0], r[1]); s.y = pk2(r[2], r[3]);
  s.z = pk2(r[4], r[5]); s.w = pk2(r[6], r[7]);
  reinterpret_cast<uint4*>(xout)[(size_t)row*8 + o] = s;
}

// ---------------- pool (max + mean over 40 nodes) -> L2 norm -> MLP head
__global__ __launch_bounds__(256) void k_pool(
    const u16* __restrict__ x, const void* __restrict__ Wp1, const void* __restrict__ bp1,
    const void* __restrict__ Wp2, const void* __restrict__ bp2,
    const int* __restrict__ dflag, void* __restrict__ out) {
  int fz = *dflag;
  int b = blockIdx.x / (NC/4);
  int cb = blockIdx.x % (NC/4);
  int t = threadIdx.x;
  int h = t & 63;
  int w = t >> 6;                 // one wave = one config
  int c = cb*4 + w;
  __shared__ float wp1[64*32];
  __shared__ float bp1s[32], wp2s[32];
  __shared__ float xs[4][64];
  for (int f = t; f < 2048; f += 256) wp1[f] = ldf(Wp1, f, fz);
  if (t < 32) { bp1s[t] = ldf(bp1, t, fz); wp2s[t] = ldf(Wp2, t, fz); }
  float mx = -3.0e38f, sm = 0.f;
  for (int j = 0; j < 40; j++) {
    float v = b2f(x[((size_t)(b*40 + j)*NC + c)*64 + h]);
    mx = fmaxf(mx, v); sm += v;
  }
  float g = mx + sm * (1.f / 40.f);
  float sq = g * g;
  #pragma unroll
  for (int off = 32; off; off >>= 1) sq += __shfl_xor(sq, off);
  float gn = g * rsqrtf(sq);
  xs[w][h] = gn;
  __syncthreads();
  int j32 = h & 31;
  float hj = bp1s[j32];
  const float* xr = xs[w];
  for (int k = 0; k < 64; k++) hj += xr[k] * wp1[k*32 + j32];
  hj = fmaxf(hj, 0.f);
  float contrib = hj * wp2s[j32];   // lanes 0-31 and 32-63 duplicate -> sum/2
  #pragma unroll
  for (int off = 32; off; off >>= 1) contrib += __shfl_xor(contrib, off);
  if (h == 0) stf(out, b*NC + c, fz, contrib * 0.5f + ldf(bp2, 0, fz));
}

extern "C" void kernel_launch(void* const* d_in, const int* in_sizes, int n_in,
                              void* d_out, int out_size, void* d_ws, size_t ws_size,
                              hipStream_t stream) {
  const void* node_feat   = d_in[0];
  const int*  node_opcode = (const int*)d_in[1];
  const void* config_feat = d_in[2];
  const int*  edge_index  = (const int*)d_in[3];
  const int*  batch       = (const int*)d_in[4];
  const void* op_emb      = d_in[5];
  const void* shape_emb   = d_in[6];
  const void* W1  = d_in[7];
  const void* b1  = d_in[8];
  const void* W2  = d_in[9];
  const void* b2  = d_in[10];
  const void* Wl0 = d_in[11];
  const void* Wr0 = d_in[12];
  const void* bg0 = d_in[13];
  const void* Wl1 = d_in[14];
  const void* Wr1 = d_in[15];
  const void* bg1 = d_in[16];
  const void* Wl2 = d_in[17];
  const void* Wr2 = d_in[18];
  const void* bg2 = d_in[19];
  const void* Wp1 = d_in[20];
  const void* bp1 = d_in[21];
  const void* Wp2 = d_in[22];
  const void* bp2 = d_in[23];

  // workspace ~159 MB (known-safe; 313 MB faulted in round 2)
  char* p = (char*)d_ws;
  int*   flag   = (int*)p;   p += 256;
  float* A_node = (float*)p; p += 400*128*4;
  float* C_cfg  = (float*)p; p += 10000*128*4;
  u16*   W2t    = (u16*)p;   p += 128*128*2;
  u16*   Wc0t   = (u16*)p;   p += 128*128*2;
  u16*   Wc1t   = (u16*)p;   p += 128*64*2;
  u16*   Wc2t   = (u16*)p;   p += 128*64*2;
  int*   offs   = (int*)p;   p += 2048;
  int*   srcl   = (int*)p;   p += 4096;
  float* deg    = (float*)p; p += 2048;
  u16*   BIG    = (u16*)p;   p += (size_t)400*1000*128*2;   // X2/[y|z] (in-place), bf16
  u16*   X      = (u16*)p;   p += (size_t)400*1000*64*2;    // sage outputs, bf16

  k_detect<<<dim3(1), dim3(64), 0, stream>>>((const u16*)W1, flag);
  k_prep<<<dim3(400), dim3(128), 0, stream>>>(node_feat, node_opcode, op_emb, shape_emb, W1, b1, flag, A_node);
  k_cfg<<<dim3(10000), dim3(128), 0, stream>>>(config_feat, W1, flag, C_cfg);
  k_wpackT<<<dim3(192), dim3(256), 0, stream>>>(W2, Wl0, Wr0, Wl1, Wr1, Wl2, Wr2, flag, W2t, Wc0t, Wc1t, Wc2t);
  k_csr<<<dim3(1), dim3(256), 0, stream>>>(edge_index, offs, srcl, deg);

  // X2 = relu(relu(A_node + C_cfg[batch]) @ W2 + b2)      -> BIG  (fused build)
  k_mgemm<128, true, true><<<dim3(3125), dim3(256), 0, stream>>>(nullptr, W2t, A_node, C_cfg, batch, b2, flag, BIG);
  // sage0: [y|z] = X2 @ [Wl0|Wr0]                         -> BIG (in-place)
  k_mgemm<128, false, false><<<dim3(3125), dim3(256), 0, stream>>>(BIG, Wc0t, nullptr, nullptr, nullptr, nullptr, flag, BIG);
  k_agg<<<dim3(12500), dim3(256), 0, stream>>>(BIG, offs, srcl, deg, bg0, flag, X);
  // sage1
  k_mgemm<64, false, false><<<dim3(3125), dim3(256), 0, stream>>>(X, Wc1t, nullptr, nullptr, nullptr, nullptr, flag, BIG);
  k_agg<<<dim3(12500), dim3(256), 0, stream>>>(BIG, offs, srcl, deg, bg1, flag, X);
  // sage2
  k_mgemm<64, false, false><<<dim3(3125), dim3(256), 0, stream>>>(X, Wc2t, nullptr, nullptr, nullptr, nullptr, flag, BIG);
  k_agg<<<dim3(12500), dim3(256), 0, stream>>>(BIG, offs, srcl, deg, bg2, flag, X);
  // pool + norm + head
  k_pool<<<dim3(2500), dim3(256), 0, stream>>>(X, Wp1, bp1, Wp2, bp2, flag, d_out);
}